// Round 5
// baseline (418.026 us; speedup 1.0000x reference)
//
#include <hip/hip_runtime.h>
#include <math.h>

// ---------------------------------------------------------------------------
// Attention: B=4, S=2048, E=1024, H=8, O=128 (fp32 in/out)
// Split-bf16 (hi+lo) MFMA for x->QK and QK^T (precision-critical), plain bf16
// for V / PV / ctx@Wo. Flash-attention (no S x S materialize).
// R1: GEMM epilogue staged through LDS -> coalesced stores.
// R2: attn BM=128 (32 q-rows/wave), DMA staging w/ XOR swizzle.
// R4: gemm staging via global_load_lds width=16; exp2-domain softmax
//     (Q pre-scaled by scale*log2e); denominator via MFMA ones-column.
// R5: attn K-loop software-pipelined (K(kt+1) DMA issued post-QK-barrier,
//     V(kt) at loop-top -> barrier drains are landed); P buffer stride-64
//     w/ 16B-chunk XOR swizzle (conflict-free writes, floor reads); gated
//     alpha-rescale; gemm epilogue LDS unioned with K-tiles -> 4 blocks/CU.
// ---------------------------------------------------------------------------

typedef __attribute__((ext_vector_type(8))) short bf16x8;   // 8 bf16 (4 VGPRs)
typedef __attribute__((ext_vector_type(4))) float f32x4;

#define MFMA(a, b, c) __builtin_amdgcn_mfma_f32_16x16x32_bf16((a), (b), (c), 0, 0, 0)
#define GLB(p) ((const __attribute__((address_space(1))) void*)(p))
#define LDS(p) ((__attribute__((address_space(3))) void*)(p))

#if __has_builtin(__builtin_amdgcn_exp2f)
#define EXP2F(x) __builtin_amdgcn_exp2f(x)
#else
#define EXP2F(x) exp2f(x)
#endif

__device__ __forceinline__ short f2bf(float f) {
    union { float f; unsigned u; } v; v.f = f;
    unsigned r = v.u + 0x7fffu + ((v.u >> 16) & 1u);   // RNE
    return (short)(r >> 16);
}
__device__ __forceinline__ float bf2f(short s) {
    union { unsigned u; float f; } v; v.u = ((unsigned)(unsigned short)s) << 16;
    return v.f;
}

// ---------------- prep kernels ----------------

__global__ __launch_bounds__(256) void split_kernel(
    const float* __restrict__ x, short* __restrict__ hi, short* __restrict__ lo, int n) {
    for (int i = blockIdx.x * blockDim.x + threadIdx.x; i < n; i += gridDim.x * blockDim.x) {
        float f = x[i];
        short h = f2bf(f);
        hi[i] = h;
        lo[i] = f2bf(f - bf2f(h));
    }
}

__global__ __launch_bounds__(256) void build_wt(
    const float* __restrict__ Wq, const float* __restrict__ Wk, const float* __restrict__ Wv,
    short* __restrict__ wth, short* __restrict__ wtl) {
    const int total = 1280 * 1024;
    for (int idx = blockIdx.x * blockDim.x + threadIdx.x; idx < total; idx += gridDim.x * blockDim.x) {
        int n = idx >> 10, k = idx & 1023;
        float f;
        if (n < 1024)      f = Wq[((size_t)(n >> 7) * 1024 + k) * 128 + (n & 127)];
        else if (n < 1152) f = Wk[(size_t)k * 128 + (n - 1024)];
        else               f = Wv[(size_t)k * 128 + (n - 1152)];
        short h = f2bf(f);
        wth[idx] = h;
        wtl[idx] = f2bf(f - bf2f(h));
    }
}

__global__ __launch_bounds__(256) void build_wot(
    const float* __restrict__ Wo, short* __restrict__ wot) {
    const int total = 1024 * 1024;
    for (int idx = blockIdx.x * blockDim.x + threadIdx.x; idx < total; idx += gridDim.x * blockDim.x) {
        int e = idx >> 10, k = idx & 1023;
        wot[idx] = f2bf(Wo[(size_t)k * 1024 + e]);
    }
}

// ---------------- GEMM: C(M x N) = A(M x 1024) @ Bt(N x 1024)^T ----------------
// K-tiles and epilogue staging share one LDS allocation (disjoint lifetimes,
// barrier-separated): 33.8 KB -> 4 blocks/CU.
template <int MODE>
__global__ __launch_bounds__(256, 4) void gemm_k(
    const short* __restrict__ Ah, const short* __restrict__ Al,
    const short* __restrict__ Bth, const short* __restrict__ Btl,
    short* __restrict__ qh, short* __restrict__ ql,
    short* __restrict__ kh, short* __restrict__ kl,
    short* __restrict__ vt, float* __restrict__ outf) {
    constexpr int K = 1024;
    __shared__ __align__(16) char smem[33792];
    short* As_h = (short*)smem;                 // 128x32 = 8192 B
    short* Bs_h = (short*)(smem + 8192);
    short* As_l = (short*)(smem + 16384);       // MODE 0 only
    short* Bs_l = (short*)(smem + 24576);
    unsigned* Ep = (unsigned*)smem;             // 64x132 u32 = 33792 B (epilogue)

    const int t = threadIdx.x;
    const int m0 = blockIdx.x * 128, n0 = blockIdx.y * 128;
    const int wave = t >> 6, lane = t & 63;
    const int wr = wave >> 1, wc = wave & 1;
    const int quad = lane >> 4, l16 = lane & 15;

    f32x4 acc[4][4];
    for (int i = 0; i < 4; ++i)
        for (int j = 0; j < 4; ++j) acc[i][j] = (f32x4){0.f, 0.f, 0.f, 0.f};

    for (int kb = 0; kb < K / 32; ++kb) {
        __syncthreads();
        // DMA staging: each matrix = 512 slots of 16 B; 2 wave-insts per wave.
        for (int i = 0; i < 2; ++i) {
            int slot = (wave * 2 + i) * 64 + lane;
            int row = slot >> 2, ch = slot & 3;
            int ldsoff = (wave * 2 + i) * 512;  // shorts; +lane*16B by HW
            size_t ga = (size_t)(m0 + row) * K + kb * 32 + ch * 8;
            size_t gb = (size_t)(n0 + row) * K + kb * 32 + ch * 8;
            __builtin_amdgcn_global_load_lds(GLB(Ah + ga), LDS(&As_h[ldsoff]), 16, 0, 0);
            __builtin_amdgcn_global_load_lds(GLB(Bth + gb), LDS(&Bs_h[ldsoff]), 16, 0, 0);
            if constexpr (MODE == 0) {
                __builtin_amdgcn_global_load_lds(GLB(Al + ga), LDS(&As_l[ldsoff]), 16, 0, 0);
                __builtin_amdgcn_global_load_lds(GLB(Btl + gb), LDS(&Bs_l[ldsoff]), 16, 0, 0);
            }
        }
        __syncthreads();

        bf16x8 a[4], b[4];
        for (int mi = 0; mi < 4; ++mi)
            a[mi] = *(const bf16x8*)&As_h[(wr * 64 + mi * 16 + l16) * 32 + quad * 8];
        for (int ni = 0; ni < 4; ++ni)
            b[ni] = *(const bf16x8*)&Bs_h[(wc * 64 + ni * 16 + l16) * 32 + quad * 8];
        for (int mi = 0; mi < 4; ++mi)
            for (int ni = 0; ni < 4; ++ni)
                acc[mi][ni] = MFMA(a[mi], b[ni], acc[mi][ni]);
        if constexpr (MODE == 0) {
            bf16x8 al[4], bl[4];
            for (int mi = 0; mi < 4; ++mi)
                al[mi] = *(const bf16x8*)&As_l[(wr * 64 + mi * 16 + l16) * 32 + quad * 8];
            for (int ni = 0; ni < 4; ++ni)
                bl[ni] = *(const bf16x8*)&Bs_l[(wc * 64 + ni * 16 + l16) * 32 + quad * 8];
            for (int mi = 0; mi < 4; ++mi)
                for (int ni = 0; ni < 4; ++ni) {
                    acc[mi][ni] = MFMA(a[mi], bl[ni], acc[mi][ni]);
                    acc[mi][ni] = MFMA(al[mi], b[ni], acc[mi][ni]);
                }
        }
    }

    // LDS-staged epilogue (C/D layout: col=l16, row=quad*4+r).
    // Q columns pre-scaled by (1/sqrt(128))*log2(e) for exp2-domain softmax.
    const float qscale = 0.12753102455195157f;
    for (int p = 0; p < 2; ++p) {
        __syncthreads();   // also separates K-loop tile reads from Ep writes
        if (wr == p) {
            for (int mi = 0; mi < 4; ++mi) {
                int rl = mi * 16 + quad * 4;
                for (int ni = 0; ni < 4; ++ni) {
                    int cl = wc * 64 + ni * 16 + l16;
                    for (int r = 0; r < 4; ++r) {
                        float v = acc[mi][ni][r];
                        unsigned pk;
                        if constexpr (MODE == 0) {
                            if (blockIdx.y < 8) v *= qscale;
                            short hv = f2bf(v);
                            short lv = f2bf(v - bf2f(hv));
                            pk = (unsigned)(unsigned short)hv |
                                 ((unsigned)(unsigned short)lv << 16);
                        } else {
                            union { float f; unsigned u; } cv; cv.f = v; pk = cv.u;
                        }
                        Ep[(rl + r) * 132 + cl] = pk;
                    }
                }
            }
        }
        __syncthreads();

        if constexpr (MODE == 1) {
            for (int j = 0; j < 8; ++j) {
                int cid = t + j * 256;
                int row = cid >> 5, c = cid & 31;
                f32x4 val;
                for (int q = 0; q < 4; ++q) {
                    union { unsigned u; float f; } cv;
                    cv.u = Ep[row * 132 + c * 4 + q];
                    val[q] = cv.f;
                }
                int gr = m0 + p * 64 + row;
                *(f32x4*)&outf[(size_t)gr * 1024 + n0 + c * 4] = val;
            }
        } else if (blockIdx.y < 9) {
            for (int j = 0; j < 4; ++j) {
                int cid = t + j * 256;
                int row = cid >> 4, c = cid & 15;
                bf16x8 hv, lv;
                for (int q = 0; q < 8; ++q) {
                    unsigned w = Ep[row * 132 + c * 8 + q];
                    hv[q] = (short)(w & 0xffffu);
                    lv[q] = (short)(w >> 16);
                }
                int gr = m0 + p * 64 + row;
                int bb = gr >> 11, s = gr & 2047;
                if (blockIdx.y < 8) {
                    size_t base = (((size_t)(bb * 8 + (n0 >> 7))) * 2048 + s) * 128 + c * 8;
                    *(bf16x8*)&qh[base] = hv;
                    *(bf16x8*)&ql[base] = lv;
                } else {
                    size_t base = ((size_t)bb * 2048 + s) * 128 + c * 8;
                    *(bf16x8*)&kh[base] = hv;
                    *(bf16x8*)&kl[base] = lv;
                }
            }
        } else {
            for (int j = 0; j < 4; ++j) {
                int cid = t + j * 256;
                int d = cid >> 3, sc = cid & 7;
                bf16x8 hv;
                for (int q = 0; q < 8; ++q) {
                    unsigned w = Ep[(sc * 8 + q) * 132 + d];
                    hv[q] = (short)(w & 0xffffu);
                }
                int gr0 = m0 + p * 64 + sc * 8;
                int bb = gr0 >> 11, s0 = gr0 & 2047;
                *(bf16x8*)&vt[((size_t)bb * 128 + d) * 2048 + s0] = hv;
            }
        }
    }
}

// ---------------- flash attention ----------------
// grid (S/128, B*H); 4 waves x 32 query rows (2 m-blocks); BN=64 keys/iter.
// Pipelined: K(kt+1) DMA issued after the post-QK barrier (hidden behind
// softmax+P+PV); V(kt) DMA at loop-top (hidden behind QK). Both barriers
// drain landed loads. P buffer: stride 64, 16B-chunk XOR swizzle.
__global__ __launch_bounds__(256, 2) void attn_k(
    const short* __restrict__ qh, const short* __restrict__ ql,
    const short* __restrict__ kh, const short* __restrict__ kl,
    const short* __restrict__ vt, short* __restrict__ ctx) {
    constexpr int S = 2048, D = 128;
    __shared__ short Kh_s[64 * 128];    // swizzled, no pad
    __shared__ short Kl_s[64 * 128];
    __shared__ short Vt_s[128 * 64];    // swizzled, no pad
    __shared__ short P_s[128 * 64];     // stride 64, chunk-XOR swizzled

    const int bh = blockIdx.y, b = bh >> 3, h = bh & 7;
    const int q0 = blockIdx.x * 128;
    const int t = threadIdx.x, wave = t >> 6, lane = t & 63;
    const int quad = lane >> 4, l16 = lane & 15;
    const int e8 = l16 & 7;             // xor-swizzle key

    // ones B-fragment: B[n=l16][k] = (n==0) ? 1.0bf16 : 0  -> C[., col0] = rowsum
    bf16x8 bones;
    {
        short o = (l16 == 0) ? (short)0x3F80 : (short)0;
        for (int j = 0; j < 8; ++j) bones[j] = o;
    }

    // Q fragments (A-layout A[m=l16][k=quad*8+j]), 2 m-blocks x 4 k-chunks
    bf16x8 qfh[2][4], qfl[2][4];
    for (int mb = 0; mb < 2; ++mb) {
        size_t qbase = ((size_t)(b * 8 + h) * S + q0 + wave * 32 + mb * 16 + l16) * D + quad * 8;
        for (int c = 0; c < 4; ++c) {
            qfh[mb][c] = *(const bf16x8*)(qh + qbase + c * 32);
            qfl[mb][c] = *(const bf16x8*)(ql + qbase + c * 32);
        }
    }

    float mrow[2][4];
    f32x4 oacc[2][8], lacc[2];
    for (int mb = 0; mb < 2; ++mb) {
        for (int r = 0; r < 4; ++r) mrow[mb][r] = -INFINITY;
        for (int oi = 0; oi < 8; ++oi) oacc[mb][oi] = (f32x4){0.f, 0.f, 0.f, 0.f};
        lacc[mb] = (f32x4){0.f, 0.f, 0.f, 0.f};
    }

    // K-staging helper pattern values (per wave)
    const int kpch = lane & 15;
    const int vpch = lane & 7;

    // peel: stage K(0)
    for (int i = 0; i < 4; ++i) {
        int rk = wave * 16 + i * 4 + (lane >> 4);
        int j = kpch ^ (rk & 7);
        size_t g = ((size_t)b * S + rk) * D + j * 8;
        int ldsoff = (wave * 16 + i * 4) * 128;
        __builtin_amdgcn_global_load_lds(GLB(kh + g), LDS(&Kh_s[ldsoff]), 16, 0, 0);
        __builtin_amdgcn_global_load_lds(GLB(kl + g), LDS(&Kl_s[ldsoff]), 16, 0, 0);
    }

    for (int kt = 0; kt < S / 64; ++kt) {
        __syncthreads();   // A: prev PV's Vt reads done; K(kt) DMA landed

        // --- stage V^T(kt): 128 rows(o) x 64(s) --- (consumed after barrier B)
        for (int i = 0; i < 4; ++i) {
            int rv = wave * 32 + i * 8 + (lane >> 3);
            int j = vpch ^ (rv & 7);
            size_t g = ((size_t)b * D + rv) * S + kt * 64 + j * 8;
            int ldsoff = (wave * 32 + i * 8) * 64;
            __builtin_amdgcn_global_load_lds(GLB(vt + g), LDS(&Vt_s[ldsoff]), 16, 0, 0);
        }

        // --- S' = Q' K^T (split: hh + lh + hl); K staged last iter ---
        f32x4 sacc[2][4];
        for (int mb = 0; mb < 2; ++mb)
            for (int ni = 0; ni < 4; ++ni) sacc[mb][ni] = (f32x4){0.f, 0.f, 0.f, 0.f};
        for (int ni = 0; ni < 4; ++ni) {
            for (int c = 0; c < 4; ++c) {
                int off = (ni * 16 + l16) * 128 + ((c * 4 + quad) ^ e8) * 8;
                bf16x8 kbh = *(const bf16x8*)&Kh_s[off];
                bf16x8 kbl = *(const bf16x8*)&Kl_s[off];
                for (int mb = 0; mb < 2; ++mb) {
                    sacc[mb][ni] = MFMA(qfh[mb][c], kbh, sacc[mb][ni]);
                    sacc[mb][ni] = MFMA(qfl[mb][c], kbh, sacc[mb][ni]);
                    sacc[mb][ni] = MFMA(qfh[mb][c], kbl, sacc[mb][ni]);
                }
            }
        }

        __syncthreads();   // B: all K reads done; Vt(kt) DMA drained

        // --- stage K(kt+1) (hidden behind softmax + P + PV) ---
        if (kt + 1 < S / 64) {
            for (int i = 0; i < 4; ++i) {
                int rk = wave * 16 + i * 4 + (lane >> 4);
                int j = kpch ^ (rk & 7);
                size_t g = ((size_t)b * S + (kt + 1) * 64 + rk) * D + j * 8;
                int ldsoff = (wave * 16 + i * 4) * 128;
                __builtin_amdgcn_global_load_lds(GLB(kh + g), LDS(&Kh_s[ldsoff]), 16, 0, 0);
                __builtin_amdgcn_global_load_lds(GLB(kl + g), LDS(&Kl_s[ldsoff]), 16, 0, 0);
            }
        }

        // --- online softmax (exp2 domain) ---
        float al[2][4];
        bool need = false;
        for (int mb = 0; mb < 2; ++mb) {
            for (int r = 0; r < 4; ++r) {
                float mx = fmaxf(fmaxf(sacc[mb][0][r], sacc[mb][1][r]),
                                 fmaxf(sacc[mb][2][r], sacc[mb][3][r]));
                for (int off = 8; off; off >>= 1) mx = fmaxf(mx, __shfl_xor(mx, off));
                float mnew = fmaxf(mrow[mb][r], mx);
                al[mb][r] = EXP2F(mrow[mb][r] - mnew);
                need |= (al[mb][r] != 1.0f);
                mrow[mb][r] = mnew;
                for (int ni = 0; ni < 4; ++ni)
                    sacc[mb][ni][r] = EXP2F(sacc[mb][ni][r] - mnew);
            }
            // P -> LDS (C-layout -> A-layout), stride 64, chunk-XOR swizzle;
            // round-half-up bf16 (cheap: +0x8000, take hi16)
            for (int ni = 0; ni < 4; ++ni)
                for (int r = 0; r < 4; ++r) {
                    int row = wave * 32 + mb * 16 + quad * 4 + r;
                    int col = ni * 16 + l16;
                    union { float f; unsigned u; } cv; cv.f = sacc[mb][ni][r];
                    unsigned u = cv.u + 0x8000u;
                    P_s[row * 64 + (((col >> 3) ^ (row & 7)) << 3) + (col & 7)] =
                        (short)(u >> 16);
                }
        }

        // --- gated rescale (skipped when no row's max moved: exp2(0)==1) ---
        if (__ballot(need)) {
            for (int mb = 0; mb < 2; ++mb)
                for (int r = 0; r < 4; ++r) {
                    float a = al[mb][r];
                    lacc[mb][r] *= a;
                    for (int oi = 0; oi < 8; ++oi) oacc[mb][oi][r] *= a;
                }
        }

        // --- O += P @ V ; l += P @ ones (MFMA) ---
        for (int c2 = 0; c2 < 2; ++c2) {
            bf16x8 pa[2];
            for (int mb = 0; mb < 2; ++mb) {
                int row = wave * 32 + mb * 16 + l16;
                pa[mb] = *(const bf16x8*)&P_s[row * 64 + (((c2 * 4 + quad) ^ e8) << 3)];
                lacc[mb] = MFMA(pa[mb], bones, lacc[mb]);
            }
            for (int oi = 0; oi < 8; ++oi) {
                int off = (oi * 16 + l16) * 64 + ((c2 * 4 + quad) ^ e8) * 8;
                bf16x8 vb = *(const bf16x8*)&Vt_s[off];
                for (int mb = 0; mb < 2; ++mb)
                    oacc[mb][oi] = MFMA(pa[mb], vb, oacc[mb][oi]);
            }
        }
    }

    // epilogue: ctx[b][s][h*128+o] bf16; l lives in col-0 lanes (l16==0)
    for (int mb = 0; mb < 2; ++mb) {
        for (int r = 0; r < 4; ++r) {
            float ls = __shfl(lacc[mb][r], lane & 48);  // broadcast from l16==0 of quad
            float inv = 1.f / ls;
            int s = q0 + wave * 32 + mb * 16 + quad * 4 + r;
            size_t base = ((size_t)b * S + s) * 1024 + h * 128;
            for (int oi = 0; oi < 8; ++oi)
                ctx[base + oi * 16 + l16] = f2bf(oacc[mb][oi][r] * inv);
        }
    }
}

// ---------------- launch ----------------

extern "C" void kernel_launch(void* const* d_in, const int* in_sizes, int n_in,
                              void* d_out, int out_size, void* d_ws, size_t ws_size,
                              hipStream_t stream) {
    const float* x  = (const float*)d_in[0];
    const float* Wq = (const float*)d_in[1];
    const float* Wk = (const float*)d_in[2];
    const float* Wv = (const float*)d_in[3];
    const float* Wo = (const float*)d_in[4];
    float* out = (float*)d_out;

    char* p = (char*)d_ws;
    auto alloc = [&](size_t bytes) { char* r = p; p += bytes; return r; };
    short* xh  = (short*)alloc(16777216);  // x hi    (8192 x 1024)
    short* xl  = (short*)alloc(16777216);  // x lo
    short* wth = (short*)alloc(2621440);   // Wt hi   (1280 x 1024)
    short* wtl = (short*)alloc(2621440);   // Wt lo
    short* wot = (short*)alloc(2097152);   // Wo^T    (1024 x 1024)
    short* qh  = (short*)alloc(16777216);  // Q hi    (B,H,S,D), pre-scaled
    short* ql  = (short*)alloc(16777216);  // Q lo
    short* kh  = (short*)alloc(2097152);   // K hi    (B,S,D)
    short* kl  = (short*)alloc(2097152);   // K lo
    short* vt  = (short*)alloc(2097152);   // V^T     (B,D,S)
    short* ctx = (short*)alloc(16777216);  // ctx     (B,S,H*D)

    split_kernel<<<dim3(2048), dim3(256), 0, stream>>>(x, xh, xl, 8192 * 1024);
    build_wt<<<dim3(1280), dim3(256), 0, stream>>>(Wq, Wk, Wv, wth, wtl);
    build_wot<<<dim3(1024), dim3(256), 0, stream>>>(Wo, wot);
    gemm_k<0><<<dim3(64, 10), dim3(256), 0, stream>>>(xh, xl, wth, wtl,
                                                      qh, ql, kh, kl, vt, nullptr);
    attn_k<<<dim3(16, 32), dim3(256), 0, stream>>>(qh, ql, kh, kl, vt, ctx);
    gemm_k<1><<<dim3(64, 8), dim3(256), 0, stream>>>(ctx, nullptr, wot, nullptr,
                                                     nullptr, nullptr, nullptr, nullptr,
                                                     nullptr, out);
}

// Round 6
// 369.830 us; speedup vs baseline: 1.1303x; 1.1303x over previous
//
#include <hip/hip_runtime.h>
#include <math.h>

// ---------------------------------------------------------------------------
// Attention: B=4, S=2048, E=1024, H=8, O=128 (fp32 in/out)
// Split-bf16 (hi+lo) MFMA for x->QK and QK^T (precision-critical), plain bf16
// for V / PV / ctx@Wo. Flash-attention (no S x S materialize).
// R1: GEMM epilogue staged through LDS -> coalesced stores.
// R2: attn BM=128 (32 q-rows/wave), DMA staging w/ XOR swizzle.
// R4: gemm staging via global_load_lds width=16; exp2-domain softmax
//     (Q pre-scaled by scale*log2e); denominator via MFMA ones-column.
// R5: gemm epilogue LDS unioned with K-tiles -> 4 blocks/CU (KEPT: -26us).
//     attn split-barrier pipelining REGRESSED (180->243us, pure stall:
//     MfmaUtil*dur invariant) -> R6 reverts attn to the R4 2-barrier
//     structure (DMA issued between barriers, single drain point).
// ---------------------------------------------------------------------------

typedef __attribute__((ext_vector_type(8))) short bf16x8;   // 8 bf16 (4 VGPRs)
typedef __attribute__((ext_vector_type(4))) float f32x4;

#define MFMA(a, b, c) __builtin_amdgcn_mfma_f32_16x16x32_bf16((a), (b), (c), 0, 0, 0)
#define GLB(p) ((const __attribute__((address_space(1))) void*)(p))
#define LDS(p) ((__attribute__((address_space(3))) void*)(p))

#if __has_builtin(__builtin_amdgcn_exp2f)
#define EXP2F(x) __builtin_amdgcn_exp2f(x)
#else
#define EXP2F(x) exp2f(x)
#endif

__device__ __forceinline__ short f2bf(float f) {
    union { float f; unsigned u; } v; v.f = f;
    unsigned r = v.u + 0x7fffu + ((v.u >> 16) & 1u);   // RNE
    return (short)(r >> 16);
}
__device__ __forceinline__ float bf2f(short s) {
    union { unsigned u; float f; } v; v.u = ((unsigned)(unsigned short)s) << 16;
    return v.f;
}

// ---------------- prep kernels ----------------

__global__ __launch_bounds__(256) void split_kernel(
    const float* __restrict__ x, short* __restrict__ hi, short* __restrict__ lo, int n) {
    for (int i = blockIdx.x * blockDim.x + threadIdx.x; i < n; i += gridDim.x * blockDim.x) {
        float f = x[i];
        short h = f2bf(f);
        hi[i] = h;
        lo[i] = f2bf(f - bf2f(h));
    }
}

__global__ __launch_bounds__(256) void build_wt(
    const float* __restrict__ Wq, const float* __restrict__ Wk, const float* __restrict__ Wv,
    short* __restrict__ wth, short* __restrict__ wtl) {
    const int total = 1280 * 1024;
    for (int idx = blockIdx.x * blockDim.x + threadIdx.x; idx < total; idx += gridDim.x * blockDim.x) {
        int n = idx >> 10, k = idx & 1023;
        float f;
        if (n < 1024)      f = Wq[((size_t)(n >> 7) * 1024 + k) * 128 + (n & 127)];
        else if (n < 1152) f = Wk[(size_t)k * 128 + (n - 1024)];
        else               f = Wv[(size_t)k * 128 + (n - 1152)];
        short h = f2bf(f);
        wth[idx] = h;
        wtl[idx] = f2bf(f - bf2f(h));
    }
}

__global__ __launch_bounds__(256) void build_wot(
    const float* __restrict__ Wo, short* __restrict__ wot) {
    const int total = 1024 * 1024;
    for (int idx = blockIdx.x * blockDim.x + threadIdx.x; idx < total; idx += gridDim.x * blockDim.x) {
        int e = idx >> 10, k = idx & 1023;
        wot[idx] = f2bf(Wo[(size_t)k * 1024 + e]);
    }
}

// ---------------- GEMM: C(M x N) = A(M x 1024) @ Bt(N x 1024)^T ----------------
// K-tiles and epilogue staging share one LDS allocation (disjoint lifetimes,
// barrier-separated): 33.8 KB -> 4 blocks/CU.
template <int MODE>
__global__ __launch_bounds__(256, 4) void gemm_k(
    const short* __restrict__ Ah, const short* __restrict__ Al,
    const short* __restrict__ Bth, const short* __restrict__ Btl,
    short* __restrict__ qh, short* __restrict__ ql,
    short* __restrict__ kh, short* __restrict__ kl,
    short* __restrict__ vt, float* __restrict__ outf) {
    constexpr int K = 1024;
    __shared__ __align__(16) char smem[33792];
    short* As_h = (short*)smem;                 // 128x32 = 8192 B
    short* Bs_h = (short*)(smem + 8192);
    short* As_l = (short*)(smem + 16384);       // MODE 0 only
    short* Bs_l = (short*)(smem + 24576);
    unsigned* Ep = (unsigned*)smem;             // 64x132 u32 = 33792 B (epilogue)

    const int t = threadIdx.x;
    const int m0 = blockIdx.x * 128, n0 = blockIdx.y * 128;
    const int wave = t >> 6, lane = t & 63;
    const int wr = wave >> 1, wc = wave & 1;
    const int quad = lane >> 4, l16 = lane & 15;

    f32x4 acc[4][4];
    for (int i = 0; i < 4; ++i)
        for (int j = 0; j < 4; ++j) acc[i][j] = (f32x4){0.f, 0.f, 0.f, 0.f};

    for (int kb = 0; kb < K / 32; ++kb) {
        __syncthreads();
        // DMA staging: each matrix = 512 slots of 16 B; 2 wave-insts per wave.
        for (int i = 0; i < 2; ++i) {
            int slot = (wave * 2 + i) * 64 + lane;
            int row = slot >> 2, ch = slot & 3;
            int ldsoff = (wave * 2 + i) * 512;  // shorts; +lane*16B by HW
            size_t ga = (size_t)(m0 + row) * K + kb * 32 + ch * 8;
            size_t gb = (size_t)(n0 + row) * K + kb * 32 + ch * 8;
            __builtin_amdgcn_global_load_lds(GLB(Ah + ga), LDS(&As_h[ldsoff]), 16, 0, 0);
            __builtin_amdgcn_global_load_lds(GLB(Bth + gb), LDS(&Bs_h[ldsoff]), 16, 0, 0);
            if constexpr (MODE == 0) {
                __builtin_amdgcn_global_load_lds(GLB(Al + ga), LDS(&As_l[ldsoff]), 16, 0, 0);
                __builtin_amdgcn_global_load_lds(GLB(Btl + gb), LDS(&Bs_l[ldsoff]), 16, 0, 0);
            }
        }
        __syncthreads();

        bf16x8 a[4], b[4];
        for (int mi = 0; mi < 4; ++mi)
            a[mi] = *(const bf16x8*)&As_h[(wr * 64 + mi * 16 + l16) * 32 + quad * 8];
        for (int ni = 0; ni < 4; ++ni)
            b[ni] = *(const bf16x8*)&Bs_h[(wc * 64 + ni * 16 + l16) * 32 + quad * 8];
        for (int mi = 0; mi < 4; ++mi)
            for (int ni = 0; ni < 4; ++ni)
                acc[mi][ni] = MFMA(a[mi], b[ni], acc[mi][ni]);
        if constexpr (MODE == 0) {
            bf16x8 al[4], bl[4];
            for (int mi = 0; mi < 4; ++mi)
                al[mi] = *(const bf16x8*)&As_l[(wr * 64 + mi * 16 + l16) * 32 + quad * 8];
            for (int ni = 0; ni < 4; ++ni)
                bl[ni] = *(const bf16x8*)&Bs_l[(wc * 64 + ni * 16 + l16) * 32 + quad * 8];
            for (int mi = 0; mi < 4; ++mi)
                for (int ni = 0; ni < 4; ++ni) {
                    acc[mi][ni] = MFMA(a[mi], bl[ni], acc[mi][ni]);
                    acc[mi][ni] = MFMA(al[mi], b[ni], acc[mi][ni]);
                }
        }
    }

    // LDS-staged epilogue (C/D layout: col=l16, row=quad*4+r).
    // Q columns pre-scaled by (1/sqrt(128))*log2(e) for exp2-domain softmax.
    const float qscale = 0.12753102455195157f;
    for (int p = 0; p < 2; ++p) {
        __syncthreads();   // also separates K-loop tile reads from Ep writes
        if (wr == p) {
            for (int mi = 0; mi < 4; ++mi) {
                int rl = mi * 16 + quad * 4;
                for (int ni = 0; ni < 4; ++ni) {
                    int cl = wc * 64 + ni * 16 + l16;
                    for (int r = 0; r < 4; ++r) {
                        float v = acc[mi][ni][r];
                        unsigned pk;
                        if constexpr (MODE == 0) {
                            if (blockIdx.y < 8) v *= qscale;
                            short hv = f2bf(v);
                            short lv = f2bf(v - bf2f(hv));
                            pk = (unsigned)(unsigned short)hv |
                                 ((unsigned)(unsigned short)lv << 16);
                        } else {
                            union { float f; unsigned u; } cv; cv.f = v; pk = cv.u;
                        }
                        Ep[(rl + r) * 132 + cl] = pk;
                    }
                }
            }
        }
        __syncthreads();

        if constexpr (MODE == 1) {
            for (int j = 0; j < 8; ++j) {
                int cid = t + j * 256;
                int row = cid >> 5, c = cid & 31;
                f32x4 val;
                for (int q = 0; q < 4; ++q) {
                    union { unsigned u; float f; } cv;
                    cv.u = Ep[row * 132 + c * 4 + q];
                    val[q] = cv.f;
                }
                int gr = m0 + p * 64 + row;
                *(f32x4*)&outf[(size_t)gr * 1024 + n0 + c * 4] = val;
            }
        } else if (blockIdx.y < 9) {
            for (int j = 0; j < 4; ++j) {
                int cid = t + j * 256;
                int row = cid >> 4, c = cid & 15;
                bf16x8 hv, lv;
                for (int q = 0; q < 8; ++q) {
                    unsigned w = Ep[row * 132 + c * 8 + q];
                    hv[q] = (short)(w & 0xffffu);
                    lv[q] = (short)(w >> 16);
                }
                int gr = m0 + p * 64 + row;
                int bb = gr >> 11, s = gr & 2047;
                if (blockIdx.y < 8) {
                    size_t base = (((size_t)(bb * 8 + (n0 >> 7))) * 2048 + s) * 128 + c * 8;
                    *(bf16x8*)&qh[base] = hv;
                    *(bf16x8*)&ql[base] = lv;
                } else {
                    size_t base = ((size_t)bb * 2048 + s) * 128 + c * 8;
                    *(bf16x8*)&kh[base] = hv;
                    *(bf16x8*)&kl[base] = lv;
                }
            }
        } else {
            for (int j = 0; j < 4; ++j) {
                int cid = t + j * 256;
                int d = cid >> 3, sc = cid & 7;
                bf16x8 hv;
                for (int q = 0; q < 8; ++q) {
                    unsigned w = Ep[(sc * 8 + q) * 132 + d];
                    hv[q] = (short)(w & 0xffffu);
                }
                int gr0 = m0 + p * 64 + sc * 8;
                int bb = gr0 >> 11, s0 = gr0 & 2047;
                *(bf16x8*)&vt[((size_t)bb * 128 + d) * 2048 + s0] = hv;
            }
        }
    }
}

// ---------------- flash attention (R4 structure) ----------------
// grid (S/128, B*H); 4 waves x 32 query rows (2 m-blocks); BN=64 keys/iter.
// K/V staged via global_load_lds with XOR-swizzled chunks between the two
// barriers (single drain point; wave-level overlap hides the rest).
__global__ __launch_bounds__(256, 2) void attn_k(
    const short* __restrict__ qh, const short* __restrict__ ql,
    const short* __restrict__ kh, const short* __restrict__ kl,
    const short* __restrict__ vt, short* __restrict__ ctx) {
    constexpr int S = 2048, D = 128;
    __shared__ short Kh_s[64 * 128];    // swizzled, no pad
    __shared__ short Kl_s[64 * 128];
    __shared__ short Vt_s[128 * 64];    // swizzled, no pad
    __shared__ short P_s[128 * 72];     // per-wave 32-row slices, stride 64+8

    const int bh = blockIdx.y, b = bh >> 3, h = bh & 7;
    const int q0 = blockIdx.x * 128;
    const int t = threadIdx.x, wave = t >> 6, lane = t & 63;
    const int quad = lane >> 4, l16 = lane & 15;
    const int e8 = l16 & 7;             // xor-swizzle key

    // ones B-fragment: B[n=l16][k] = (n==0) ? 1.0bf16 : 0  -> C[., col0] = rowsum
    bf16x8 bones;
    {
        short o = (l16 == 0) ? (short)0x3F80 : (short)0;
        for (int j = 0; j < 8; ++j) bones[j] = o;
    }

    // Q fragments (A-layout A[m=l16][k=quad*8+j]), 2 m-blocks x 4 k-chunks
    bf16x8 qfh[2][4], qfl[2][4];
    for (int mb = 0; mb < 2; ++mb) {
        size_t qbase = ((size_t)(b * 8 + h) * S + q0 + wave * 32 + mb * 16 + l16) * D + quad * 8;
        for (int c = 0; c < 4; ++c) {
            qfh[mb][c] = *(const bf16x8*)(qh + qbase + c * 32);
            qfl[mb][c] = *(const bf16x8*)(ql + qbase + c * 32);
        }
    }

    float mrow[2][4];
    f32x4 oacc[2][8], lacc[2];
    for (int mb = 0; mb < 2; ++mb) {
        for (int r = 0; r < 4; ++r) mrow[mb][r] = -INFINITY;
        for (int oi = 0; oi < 8; ++oi) oacc[mb][oi] = (f32x4){0.f, 0.f, 0.f, 0.f};
        lacc[mb] = (f32x4){0.f, 0.f, 0.f, 0.f};
    }

    for (int kt = 0; kt < S / 64; ++kt) {
        __syncthreads();  // protect LDS reuse
        // --- stage K hi/lo: 64 rows x 128 ---
        {
            int pch = lane & 15;
            for (int i = 0; i < 4; ++i) {
                int rk = wave * 16 + i * 4 + (lane >> 4);
                int j = pch ^ (rk & 7);
                size_t g = ((size_t)b * S + kt * 64 + rk) * D + j * 8;
                int ldsoff = (wave * 16 + i * 4) * 128;
                __builtin_amdgcn_global_load_lds(GLB(kh + g), LDS(&Kh_s[ldsoff]), 16, 0, 0);
                __builtin_amdgcn_global_load_lds(GLB(kl + g), LDS(&Kl_s[ldsoff]), 16, 0, 0);
            }
        }
        // --- stage V^T: 128 rows(o) x 64(s) ---
        {
            int pch = lane & 7;
            for (int i = 0; i < 4; ++i) {
                int rv = wave * 32 + i * 8 + (lane >> 3);
                int j = pch ^ (rv & 7);
                size_t g = ((size_t)b * D + rv) * S + kt * 64 + j * 8;
                int ldsoff = (wave * 32 + i * 8) * 64;
                __builtin_amdgcn_global_load_lds(GLB(vt + g), LDS(&Vt_s[ldsoff]), 16, 0, 0);
            }
        }
        __syncthreads();

        // --- S' = Q' K^T (split: hh + lh + hl); scores already * scale*log2e ---
        f32x4 sacc[2][4];
        for (int mb = 0; mb < 2; ++mb)
            for (int ni = 0; ni < 4; ++ni) sacc[mb][ni] = (f32x4){0.f, 0.f, 0.f, 0.f};
        for (int ni = 0; ni < 4; ++ni) {
            for (int c = 0; c < 4; ++c) {
                int off = (ni * 16 + l16) * 128 + ((c * 4 + quad) ^ e8) * 8;
                bf16x8 kbh = *(const bf16x8*)&Kh_s[off];
                bf16x8 kbl = *(const bf16x8*)&Kl_s[off];
                for (int mb = 0; mb < 2; ++mb) {
                    sacc[mb][ni] = MFMA(qfh[mb][c], kbh, sacc[mb][ni]);
                    sacc[mb][ni] = MFMA(qfl[mb][c], kbh, sacc[mb][ni]);
                    sacc[mb][ni] = MFMA(qfh[mb][c], kbl, sacc[mb][ni]);
                }
            }
        }

        // --- online softmax (exp2 domain); rows quad*4+r per m-block ---
        for (int mb = 0; mb < 2; ++mb) {
            for (int r = 0; r < 4; ++r) {
                float mx = fmaxf(fmaxf(sacc[mb][0][r], sacc[mb][1][r]),
                                 fmaxf(sacc[mb][2][r], sacc[mb][3][r]));
                for (int off = 8; off; off >>= 1) mx = fmaxf(mx, __shfl_xor(mx, off));
                float mnew = fmaxf(mrow[mb][r], mx);
                float alpha = EXP2F(mrow[mb][r] - mnew);
                mrow[mb][r] = mnew;
                for (int ni = 0; ni < 4; ++ni)
                    sacc[mb][ni][r] = EXP2F(sacc[mb][ni][r] - mnew);
                lacc[mb][r] *= alpha;
                for (int oi = 0; oi < 8; ++oi) oacc[mb][oi][r] *= alpha;
            }
            // P -> LDS (C-layout -> A-layout); round-half-up bf16 (2 ops)
            for (int ni = 0; ni < 4; ++ni)
                for (int r = 0; r < 4; ++r) {
                    union { float f; unsigned u; } cv; cv.f = sacc[mb][ni][r];
                    P_s[(wave * 32 + mb * 16 + quad * 4 + r) * 72 + ni * 16 + l16] =
                        (short)((cv.u + 0x8000u) >> 16);
                }
        }

        // --- O += P @ V ; l += P @ ones (MFMA) ---
        for (int c2 = 0; c2 < 2; ++c2) {
            bf16x8 pa[2];
            for (int mb = 0; mb < 2; ++mb) {
                pa[mb] = *(const bf16x8*)&P_s[(wave * 32 + mb * 16 + l16) * 72 + c2 * 32 + quad * 8];
                lacc[mb] = MFMA(pa[mb], bones, lacc[mb]);
            }
            for (int oi = 0; oi < 8; ++oi) {
                int off = (oi * 16 + l16) * 64 + ((c2 * 4 + quad) ^ e8) * 8;
                bf16x8 vb = *(const bf16x8*)&Vt_s[off];
                for (int mb = 0; mb < 2; ++mb)
                    oacc[mb][oi] = MFMA(pa[mb], vb, oacc[mb][oi]);
            }
        }
    }

    // epilogue: ctx[b][s][h*128+o] bf16; l lives in col-0 lanes (l16==0)
    for (int mb = 0; mb < 2; ++mb) {
        for (int r = 0; r < 4; ++r) {
            float ls = __shfl(lacc[mb][r], lane & 48);  // broadcast from l16==0 of quad
            float inv = 1.f / ls;
            int s = q0 + wave * 32 + mb * 16 + quad * 4 + r;
            size_t base = ((size_t)b * S + s) * 1024 + h * 128;
            for (int oi = 0; oi < 8; ++oi)
                ctx[base + oi * 16 + l16] = f2bf(oacc[mb][oi][r] * inv);
        }
    }
}

// ---------------- launch ----------------

extern "C" void kernel_launch(void* const* d_in, const int* in_sizes, int n_in,
                              void* d_out, int out_size, void* d_ws, size_t ws_size,
                              hipStream_t stream) {
    const float* x  = (const float*)d_in[0];
    const float* Wq = (const float*)d_in[1];
    const float* Wk = (const float*)d_in[2];
    const float* Wv = (const float*)d_in[3];
    const float* Wo = (const float*)d_in[4];
    float* out = (float*)d_out;

    char* p = (char*)d_ws;
    auto alloc = [&](size_t bytes) { char* r = p; p += bytes; return r; };
    short* xh  = (short*)alloc(16777216);  // x hi    (8192 x 1024)
    short* xl  = (short*)alloc(16777216);  // x lo
    short* wth = (short*)alloc(2621440);   // Wt hi   (1280 x 1024)
    short* wtl = (short*)alloc(2621440);   // Wt lo
    short* wot = (short*)alloc(2097152);   // Wo^T    (1024 x 1024)
    short* qh  = (short*)alloc(16777216);  // Q hi    (B,H,S,D), pre-scaled
    short* ql  = (short*)alloc(16777216);  // Q lo
    short* kh  = (short*)alloc(2097152);   // K hi    (B,S,D)
    short* kl  = (short*)alloc(2097152);   // K lo
    short* vt  = (short*)alloc(2097152);   // V^T     (B,D,S)
    short* ctx = (short*)alloc(16777216);  // ctx     (B,S,H*D)

    split_kernel<<<dim3(2048), dim3(256), 0, stream>>>(x, xh, xl, 8192 * 1024);
    build_wt<<<dim3(1280), dim3(256), 0, stream>>>(Wq, Wk, Wv, wth, wtl);
    build_wot<<<dim3(1024), dim3(256), 0, stream>>>(Wo, wot);
    gemm_k<0><<<dim3(64, 10), dim3(256), 0, stream>>>(xh, xl, wth, wtl,
                                                      qh, ql, kh, kl, vt, nullptr);
    attn_k<<<dim3(16, 32), dim3(256), 0, stream>>>(qh, ql, kh, kl, vt, ctx);
    gemm_k<1><<<dim3(64, 8), dim3(256), 0, stream>>>(ctx, nullptr, wot, nullptr,
                                                     nullptr, nullptr, nullptr, nullptr,
                                                     nullptr, out);
}